// Round 14
// baseline (250.886 us; speedup 1.0000x reference)
//
#include <hip/hip_runtime.h>
#include <hip/hip_bf16.h>

// Block_4776003633552: transformer block, B=4 T=2048 C=512 H=8 D=64. fp32 I/O.
// Reference quirks: scale = C^-0.5; softmax over QUERY axis (axis=-2) =>
//   out_t = sum_{s<=t} exp(sc*q_t.k_s) * v_s / L_s,  L_s = sum_{t>=s} exp(sc*q_t.k_s).
// Round 14: LN2 decomposed -> tiny ln_stats (mu,rstd per row) + normalization
// fused into W1's VGPR A-staging (g2/beta2 pre-converted to bf16 in prep).
// Kills the h2 round-trip (16 MB) and the LN2 kernel. reduce_w2 widened to 8.
// Rest = r13 (BK=64 XOR-swizzled GEMMs, fused Wo, parity-split attention).

typedef __hip_bfloat16 bf16;
typedef __bf16 b8v __attribute__((ext_vector_type(8)));   // MFMA A/B fragment (8 bf16)
typedef float  f32x4 __attribute__((ext_vector_type(4))); // MFMA C/D fragment
typedef short  s8v  __attribute__((ext_vector_type(8)));  // 16B bf16 copy chunk
typedef short  s4v  __attribute__((ext_vector_type(4)));  // 8B packed chunk

#define B_   4
#define T_   2048
#define C_   512
#define H_   8
#define D_   64
#define BT_  (B_ * T_)
#define C4_  (4 * C_)
#define EPS_ 1e-5f
#define SCALE2_ 0.06375872465908385f  // (1/sqrt(512)) * log2(e): exp(x*s)=2^(x*s*log2e)

#define MFMA16(a, b, c) __builtin_amdgcn_mfma_f32_16x16x32_bf16(a, b, c, 0, 0, 0)
#define EXP2F(x) __builtin_amdgcn_exp2f(x)

static __device__ __forceinline__ float b2f(bf16 x) { return __bfloat162float(x); }
static __device__ __forceinline__ bf16  f2b(float x) { return __float2bfloat16(x); }
static __device__ __forceinline__ short f2bs(float x) {
    bf16 h = f2b(x);
    return __builtin_bit_cast(short, h);
}
static __device__ __forceinline__ float s2f(short x) {
    return b2f(__builtin_bit_cast(bf16, x));
}
// packed 2xfp32 -> 2xbf16 (v_cvt_pk_bf16_f32); memcpy because __hip_bfloat162
// is not trivially copyable (bit_cast rejected).
static __device__ __forceinline__ unsigned int pk2(float a, float b) {
    float2 f;
    f.x = a;
    f.y = b;
    __hip_bfloat162 h = __float22bfloat162_rn(f);
    unsigned int u;
    __builtin_memcpy(&u, &h, 4);
    return u;
}

// ---------------- LayerNorm body (LN1, inside prep) ----------------
static __device__ __forceinline__ float ldv(const float* p) { return *p; }
static __device__ __forceinline__ float ldv(const bf16* p)  { return b2f(*p); }

template <typename TIN>
static __device__ __forceinline__ void ln_body(const TIN* __restrict__ xr,
                                               const float* __restrict__ g,
                                               const float* __restrict__ be,
                                               bf16* __restrict__ orow,
                                               float* ws, float* wsq) {
    const int tid = threadIdx.x;
    float v0 = ldv(xr + tid * 2);
    float v1 = ldv(xr + tid * 2 + 1);
    float s = v0 + v1;
    float sq = v0 * v0 + v1 * v1;
    #pragma unroll
    for (int o = 32; o > 0; o >>= 1) {
        s += __shfl_down(s, o);
        sq += __shfl_down(sq, o);
    }
    const int wid = tid >> 6, lane = tid & 63;
    if (lane == 0) { ws[wid] = s; wsq[wid] = sq; }
    __syncthreads();
    if (tid == 0) {
        float ts = 0.f, tq = 0.f;
        #pragma unroll
        for (int i = 0; i < 4; i++) { ts += ws[i]; tq += wsq[i]; }
        float mu = ts * (1.f / C_);
        float var = tq * (1.f / C_) - mu * mu;
        ws[4] = mu;
        wsq[4] = rsqrtf(var + EPS_);
    }
    __syncthreads();
    const float mu = ws[4], rstd = wsq[4];
    orow[tid * 2]     = f2b((v0 - mu) * rstd * g[tid * 2]     + be[tid * 2]);
    orow[tid * 2 + 1] = f2b((v1 - mu) * rstd * g[tid * 2 + 1] + be[tid * 2 + 1]);
}

// ---------------- ln_stats: per-row (mu, rstd) of x1; 4 rows/block ----------------
__global__ __launch_bounds__(256) void ln_stats(const bf16* __restrict__ x1,
                                                float2* __restrict__ stats) {
    const int tid = threadIdx.x, lane = tid & 63, wvi = tid >> 6;
    const int row = blockIdx.x * 4 + wvi;
    const bf16* xr = x1 + (size_t)row * C_;
    s8v v = *(const s8v*)(xr + lane * 8);
    float s = 0.f, sq = 0.f;
    #pragma unroll
    for (int j = 0; j < 8; j++) {
        float f = s2f(v[j]);
        s += f;
        sq += f * f;
    }
    #pragma unroll
    for (int o = 1; o < 64; o <<= 1) {
        s += __shfl_xor(s, o);
        sq += __shfl_xor(sq, o);
    }
    if (lane == 0) {
        float mu = s * (1.f / C_);
        float var = sq * (1.f / C_) - mu * mu;
        float2 st;
        st.x = mu;
        st.y = rsqrtf(var + EPS_);
        stats[row] = st;
    }
}

// ---------------- prep: weight transposes (768) + LN1 (8192) + g2/be2 cvt (1) ----------------
__global__ __launch_bounds__(256) void prep_kernel(const float* __restrict__ Wq,
                                                   const float* __restrict__ Wk,
                                                   const float* __restrict__ Wv,
                                                   const float* __restrict__ Wo,
                                                   const float* __restrict__ W1,
                                                   const float* __restrict__ W2,
                                                   bf16* __restrict__ WqkvT,
                                                   bf16* __restrict__ WoT,
                                                   bf16* __restrict__ W1T,
                                                   bf16* __restrict__ W2T,
                                                   const float* __restrict__ x,
                                                   const float* __restrict__ g1,
                                                   const float* __restrict__ be1,
                                                   bf16* __restrict__ hbuf,
                                                   const float* __restrict__ g2,
                                                   const float* __restrict__ be2,
                                                   bf16* __restrict__ g2b,
                                                   bf16* __restrict__ be2b) {
    __shared__ float Ts[64][65];
    __shared__ float ws[8], wsq[8];
    const int tid = threadIdx.x;
    const int id = blockIdx.x;
    if (id == 768 + BT_) {  // g2/beta2 -> bf16
        g2b[tid * 2] = f2b(g2[tid * 2]);
        g2b[tid * 2 + 1] = f2b(g2[tid * 2 + 1]);
        be2b[tid * 2] = f2b(be2[tid * 2]);
        be2b[tid * 2 + 1] = f2b(be2[tid * 2 + 1]);
        return;
    }
    if (id >= 768) {  // LN1
        const int row = id - 768;
        ln_body(x + (size_t)row * C_, g1, be1, hbuf + (size_t)row * C_, ws, wsq);
        return;
    }
    if (id < 192) {
        const int sub = id / 64, rem = id % 64;
        const int xx = rem & 7, hh = rem >> 3;
        const float* src = (sub == 0 ? Wq : sub == 1 ? Wk : Wv) + (size_t)hh * C_ * D_;
        bf16* dst = WqkvT + (size_t)sub * 512 * C_;
        const int c0 = xx * 64;
        #pragma unroll
        for (int p = 0; p < 16; p++) {
            int idx = p * 256 + tid, i = idx >> 6, j = idx & 63;
            Ts[i][j] = src[(size_t)(c0 + i) * D_ + j];
        }
        __syncthreads();
        #pragma unroll
        for (int p = 0; p < 16; p++) {
            int idx = p * 256 + tid, j = idx >> 6, i = idx & 63;
            dst[(size_t)(hh * 64 + j) * C_ + c0 + i] = f2b(Ts[i][j]);
        }
    } else {
        const float* src;
        bf16* dst;
        int r0, c0, R, Cc;
        if (id < 256) {
            int rem = id - 192;
            src = Wo; dst = WoT; R = 512; Cc = 512;
            r0 = (rem & 7) * 64; c0 = (rem >> 3) * 64;
        } else if (id < 512) {
            int rem = id - 256;
            src = W1; dst = W1T; R = 512; Cc = 2048;
            r0 = (rem & 7) * 64; c0 = (rem >> 3) * 64;
        } else {
            int rem = id - 512;
            src = W2; dst = W2T; R = 2048; Cc = 512;
            r0 = (rem & 31) * 64; c0 = (rem >> 5) * 64;
        }
        #pragma unroll
        for (int p = 0; p < 16; p++) {
            int idx = p * 256 + tid, i = idx >> 6, j = idx & 63;
            Ts[i][j] = src[(size_t)(r0 + i) * Cc + c0 + j];
        }
        __syncthreads();
        #pragma unroll
        for (int p = 0; p < 16; p++) {
            int idx = p * 256 + tid, j = idx >> 6, i = idx & 63;
            dst[(size_t)(c0 + j) * R + r0 + i] = f2b(Ts[i][j]);
        }
    }
}

// ---------------- MFMA GEMM (256 thr): C[M,N] = A[M,K] @ Bt[N,K]^T ----------------
// 128x128 tile, BK=64, XOR-swizzled LDS. 4 waves (2x2 of 64x64), 32 MFMA/iter.
// MODE 4: QKV split (q,k -> qkvb; v -> vt via LDS-transposed coalesced stores).
template <int MODE>
__global__ __launch_bounds__(256) void mfma_gemm(const bf16* __restrict__ A,
                                                 const bf16* __restrict__ Bt,
                                                 const float* __restrict__ bias,
                                                 bf16* __restrict__ outb,
                                                 bf16* __restrict__ qkvb,
                                                 bf16* __restrict__ vt,
                                                 int M, int N, int K) {
    constexpr int LBSZ = (MODE == 4) ? (128 * 136) : (2 * 128 * 64);
    __shared__ __align__(16) short LB[LBSZ];
    short* const As = LB;
    short* const Bs = LB + 128 * 64;
    const int tid = threadIdx.x;
    const int lane = tid & 63, wv = tid >> 6;
    const int wm = wv >> 1, wn = wv & 1;
    const int m0 = blockIdx.x * 128, n0 = blockIdx.y * 128;
    const int lrow8 = lane >> 3;              // row within 8-row band
    const int gchunk = ((lane & 7) ^ lrow8) * 8;  // swizzled global chunk (shorts)
    const int lm = lane & 15, quad = lane >> 4;
    const int sw = lm & 7;                    // read-side swizzle key

    f32x4 acc[4][4];
    #pragma unroll
    for (int r = 0; r < 4; r++)
        #pragma unroll
        for (int c = 0; c < 4; c++) {
            f32x4 z = {0.f, 0.f, 0.f, 0.f};
            acc[r][c] = z;
        }

    for (int k0 = 0; k0 < K; k0 += 64) {
        #pragma unroll
        for (int cc = 0; cc < 4; cc++) {
            const int rb = wv * 32 + cc * 8;  // wave-uniform base row
            const bf16* ga = A + (size_t)(m0 + rb + lrow8) * K + k0 + gchunk;
            __builtin_amdgcn_global_load_lds(
                (const __attribute__((address_space(1))) void*)ga,
                (__attribute__((address_space(3))) void*)&As[rb * 64], 16, 0, 0);
            const bf16* gb = Bt + (size_t)(n0 + rb + lrow8) * K + k0 + gchunk;
            __builtin_amdgcn_global_load_lds(
                (const __attribute__((address_space(1))) void*)gb,
                (__attribute__((address_space(3))) void*)&Bs[rb * 64], 16, 0, 0);
        }
        __syncthreads();
        b8v af[4][2], bfr[4][2];
        #pragma unroll
        for (int r = 0; r < 4; r++)
            #pragma unroll
            for (int k = 0; k < 2; k++)
                af[r][k] = *(const b8v*)&As[(wm * 64 + r * 16 + lm) * 64 +
                                            (((k * 4 + quad) ^ sw) * 8)];
        #pragma unroll
        for (int c = 0; c < 4; c++)
            #pragma unroll
            for (int k = 0; k < 2; k++)
                bfr[c][k] = *(const b8v*)&Bs[(wn * 64 + c * 16 + lm) * 64 +
                                             (((k * 4 + quad) ^ sw) * 8)];
        #pragma unroll
        for (int r = 0; r < 4; r++)
            #pragma unroll
            for (int c = 0; c < 4; c++) {
                acc[r][c] = MFMA16(af[r][0], bfr[c][0], acc[r][c]);
                acc[r][c] = MFMA16(af[r][1], bfr[c][1], acc[r][c]);
            }
        __syncthreads();
    }

    if (MODE == 4 && n0 >= 1024) {
        // V section: LDS-transpose (pitch 136) then coalesced 16B vt stores.
        short* const trans = LB;  // 128 x 136 (K-loop's final barrier guards reuse)
        #pragma unroll
        for (int r = 0; r < 4; r++) {
            const int ml = wm * 64 + r * 16 + quad * 4;
            #pragma unroll
            for (int c = 0; c < 4; c++) {
                const int nl = wn * 64 + c * 16 + lm;
                s4v p;
                #pragma unroll
                for (int reg = 0; reg < 4; reg++) p[reg] = f2bs(acc[r][c][reg]);
                *(s4v*)&trans[nl * 136 + ml] = p;
            }
        }
        __syncthreads();
        const int bb = m0 >> 11, t0loc = m0 & (T_ - 1);
        #pragma unroll
        for (int itb = 0; itb < 8; itb++) {
            int id = itb * 256 + tid;
            int nr = id >> 4, mc = id & 15;
            s8v v = *(const s8v*)&trans[nr * 136 + mc * 8];
            *(s8v*)&vt[((size_t)bb * 512 + (n0 - 1024) + nr) * T_ + t0loc + mc * 8] = v;
        }
        return;
    }

    #pragma unroll
    for (int r = 0; r < 4; r++) {
        const int mbase = m0 + wm * 64 + r * 16 + quad * 4;
        #pragma unroll
        for (int c = 0; c < 4; c++) {
            const int n = n0 + wn * 64 + c * 16 + lm;
            #pragma unroll
            for (int reg = 0; reg < 4; reg++) {
                const int m = mbase + reg;
                float v = acc[r][c][reg];
                if (MODE == 1) {
                    v += bias[n];
                    v = fmaxf(v, 0.f);
                    outb[(size_t)m * N + n] = f2b(v);
                } else {  // MODE 4 q/k section
                    qkvb[(size_t)m * 1024 + n] = f2b(v);
                }
            }
        }
    }
}

// ---------------- W1 GEMM with fused LN2: ff1 = relu(LN(x1) @ W1T^T + b1) ----------------
// A staged via VGPR: normalize x1 with per-row (mu,rstd) + bf16 affine during
// the ds_write. Same XOR-swizzle invariant as the DMA path. 256 thr, BK=64.
__global__ __launch_bounds__(256) void mfma_gemm_ln(const bf16* __restrict__ x1,
                                                    const float2* __restrict__ stats,
                                                    const bf16* __restrict__ g2b,
                                                    const bf16* __restrict__ be2b,
                                                    const bf16* __restrict__ Bt,
                                                    const float* __restrict__ bias,
                                                    bf16* __restrict__ outb,
                                                    int M, int N, int K) {
    __shared__ short As[128 * 64];
    __shared__ short Bs[128 * 64];
    const int tid = threadIdx.x;
    const int lane = tid & 63, wv = tid >> 6;
    const int wm = wv >> 1, wn = wv & 1;
    const int m0 = blockIdx.x * 128, n0 = blockIdx.y * 128;
    const int lrow8 = lane >> 3;
    const int gchunk = ((lane & 7) ^ lrow8) * 8;
    const int lm = lane & 15, quad = lane >> 4;
    const int sw = lm & 7;
    // A staging: 1024 chunks, 4 per thread; LDS pos p of row r holds chunk p^(r&7)
    int arow[4], apos[4], asrc[4];
    float2 st[4];
    #pragma unroll
    for (int cc = 0; cc < 4; cc++) {
        int id = cc * 256 + tid;
        arow[cc] = id >> 3;
        apos[cc] = id & 7;
        asrc[cc] = (apos[cc] ^ (arow[cc] & 7)) * 8;
        st[cc] = stats[m0 + arow[cc]];
    }

    f32x4 acc[4][4];
    #pragma unroll
    for (int r = 0; r < 4; r++)
        #pragma unroll
        for (int c = 0; c < 4; c++) {
            f32x4 z = {0.f, 0.f, 0.f, 0.f};
            acc[r][c] = z;
        }

    for (int k0 = 0; k0 < K; k0 += 64) {
        // normalize + commit A tile
        #pragma unroll
        for (int cc = 0; cc < 4; cc++) {
            const int ch = k0 + asrc[cc];
            s8v xv = *(const s8v*)(x1 + (size_t)(m0 + arow[cc]) * K + ch);
            s8v gv = *(const s8v*)(g2b + ch);
            s8v bv = *(const s8v*)(be2b + ch);
            const float mu = st[cc].x, rstd = st[cc].y;
            s8v o;
            #pragma unroll
            for (int j = 0; j < 8; j++)
                o[j] = f2bs((s2f(xv[j]) - mu) * rstd * s2f(gv[j]) + s2f(bv[j]));
            *(s8v*)&As[arow[cc] * 64 + apos[cc] * 8] = o;
        }
        // B via DMA
        #pragma unroll
        for (int cc = 0; cc < 4; cc++) {
            const int rb = wv * 32 + cc * 8;
            const bf16* gb = Bt + (size_t)(n0 + rb + lrow8) * K + k0 + gchunk;
            __builtin_amdgcn_global_load_lds(
                (const __attribute__((address_space(1))) void*)gb,
                (__attribute__((address_space(3))) void*)&Bs[rb * 64], 16, 0, 0);
        }
        __syncthreads();
        b8v af[4][2], bfr[4][2];
        #pragma unroll
        for (int r = 0; r < 4; r++)
            #pragma unroll
            for (int k = 0; k < 2; k++)
                af[r][k] = *(const b8v*)&As[(wm * 64 + r * 16 + lm) * 64 +
                                            (((k * 4 + quad) ^ sw) * 8)];
        #pragma unroll
        for (int c = 0; c < 4; c++)
            #pragma unroll
            for (int k = 0; k < 2; k++)
                bfr[c][k] = *(const b8v*)&Bs[(wn * 64 + c * 16 + lm) * 64 +
                                             (((k * 4 + quad) ^ sw) * 8)];
        #pragma unroll
        for (int r = 0; r < 4; r++)
            #pragma unroll
            for (int c = 0; c < 4; c++) {
                acc[r][c] = MFMA16(af[r][0], bfr[c][0], acc[r][c]);
                acc[r][c] = MFMA16(af[r][1], bfr[c][1], acc[r][c]);
            }
        __syncthreads();
    }

    #pragma unroll
    for (int r = 0; r < 4; r++) {
        const int mbase = m0 + wm * 64 + r * 16 + quad * 4;
        #pragma unroll
        for (int c = 0; c < 4; c++) {
            const int n = n0 + wn * 64 + c * 16 + lm;
            #pragma unroll
            for (int reg = 0; reg < 4; reg++) {
                const int m = mbase + reg;
                float v = acc[r][c][reg] + bias[n];
                v = fmaxf(v, 0.f);
                outb[(size_t)m * N + n] = f2b(v);
            }
        }
    }
}

// ---------------- Split-K MFMA GEMM: partial[z] = A[:, zKh:(z+1)Kh] @ Bt^T ----------------
__global__ __launch_bounds__(256) void mfma_gemm_sk(const bf16* __restrict__ A,
                                                    const bf16* __restrict__ Bt,
                                                    bf16* __restrict__ part,
                                                    int M, int N, int K, int Khalf) {
    __shared__ short As[128 * 64];
    __shared__ short Bs[128 * 64];
    const int tid = threadIdx.x;
    const int lane = tid & 63, wv = tid >> 6;
    const int wm = wv >> 1, wn = wv & 1;
    const int m0 = blockIdx.x * 128, n0 = blockIdx.y * 128;
    const int kbase = blockIdx.z * Khalf;
    const int lrow8 = lane >> 3;
    const int gchunk = ((lane & 7) ^ lrow8) * 8;
    const int lm = lane & 15, quad = lane >> 4;
    const int sw = lm & 7;

    f32x4 acc[4][4];
    #pragma unroll
    for (int r = 0; r < 4; r++)
        #pragma unroll
        for (int c = 0; c < 4; c++) {
            f32x4 z = {0.f, 0.f, 0.f, 0.f};
            acc[r][c] = z;
        }

    for (int kk = 0; kk < Khalf; kk += 64) {
        const int k0 = kbase + kk;
        #pragma unroll
        for (int cc = 0; cc < 4; cc++) {
            const int rb = wv * 32 + cc * 8;
            const bf16* ga = A + (size_t)(m0 + rb + lrow8) * K + k0 + gchunk;
            __builtin_amdgcn_global_load_lds(
                (const __attribute__((address_space(1))) void*)ga,
                (__attribute__((address_space(3))) void*)&As[rb * 64], 16, 0, 0);
            const bf16* gb = Bt + (size_t)(n0 + rb + lrow8) * K + k0 + gchunk;
            __builtin_amdgcn_global_load_lds(
                (const __attribute__((address_space(1))) void*)gb,
                (__attribute__((address_space(3))) void*)&Bs[rb * 64], 16, 0, 0);
        }
        __syncthreads();
        b8v af[4][2], bfr[4][2];
        #pragma unroll
        for (int r = 0; r < 4; r++)
            #pragma unroll
            for (int k = 0; k < 2; k++)
                af[r][k] = *(const b8v*)&As[(wm * 64 + r * 16 + lm) * 64 +
                                            (((k * 4 + quad) ^ sw) * 8)];
        #pragma unroll
        for (int c = 0; c < 4; c++)
            #pragma unroll
            for (int k = 0; k < 2; k++)
                bfr[c][k] = *(const b8v*)&Bs[(wn * 64 + c * 16 + lm) * 64 +
                                             (((k * 4 + quad) ^ sw) * 8)];
        #pragma unroll
        for (int r = 0; r < 4; r++)
            #pragma unroll
            for (int c = 0; c < 4; c++) {
                acc[r][c] = MFMA16(af[r][0], bfr[c][0], acc[r][c]);
                acc[r][c] = MFMA16(af[r][1], bfr[c][1], acc[r][c]);
            }
        __syncthreads();
    }

    bf16* pz = part + (size_t)blockIdx.z * M * N;
    #pragma unroll
    for (int r = 0; r < 4; r++) {
        const int mbase = m0 + wm * 64 + r * 16 + quad * 4;
        #pragma unroll
        for (int c = 0; c < 4; c++) {
            const int n = n0 + wn * 64 + c * 16 + lm;
            #pragma unroll
            for (int reg = 0; reg < 4; reg++)
                pz[(size_t)(mbase + reg) * N + n] = f2b(acc[r][c][reg]);
        }
    }
}

// ---------------- reduce: out = p0 + p1 + bias + res (fp32 out, 8-wide) ----------------
__global__ __launch_bounds__(256) void reduce_w2(const bf16* __restrict__ part,
                                                 const float* __restrict__ bias,
                                                 const bf16* __restrict__ res,
                                                 float* __restrict__ out) {
    const size_t i = ((size_t)blockIdx.x * 256 + threadIdx.x) * 8;
    const int n = (int)(i & (C_ - 1));
    s8v a = *(const s8v*)(part + i);
    s8v b = *(const s8v*)(part + (size_t)BT_ * C_ + i);
    s8v rv = *(const s8v*)(res + i);
    float4 bs0 = *(const float4*)(bias + n);
    float4 bs1 = *(const float4*)(bias + n + 4);
    float4 o0, o1;
    o0.x = s2f(a[0]) + s2f(b[0]) + bs0.x + s2f(rv[0]);
    o0.y = s2f(a[1]) + s2f(b[1]) + bs0.y + s2f(rv[1]);
    o0.z = s2f(a[2]) + s2f(b[2]) + bs0.z + s2f(rv[2]);
    o0.w = s2f(a[3]) + s2f(b[3]) + bs0.w + s2f(rv[3]);
    o1.x = s2f(a[4]) + s2f(b[4]) + bs1.x + s2f(rv[4]);
    o1.y = s2f(a[5]) + s2f(b[5]) + bs1.y + s2f(rv[5]);
    o1.z = s2f(a[6]) + s2f(b[6]) + bs1.z + s2f(rv[6]);
    o1.w = s2f(a[7]) + s2f(b[7]) + bs1.w + s2f(rv[7]);
    *(float4*)(out + i) = o0;
    *(float4*)(out + i + 4) = o1;
}

// ---------------- MFMA GEMM (512 thr) fused: x1 = (p0+p1)@WoT^T + bias + res ----------------
__global__ __launch_bounds__(512) void mfma_gemm2f(const bf16* __restrict__ p0,
                                                   const bf16* __restrict__ p1,
                                                   const bf16* __restrict__ Bt,
                                                   const float* __restrict__ bias,
                                                   const float* __restrict__ resf,
                                                   bf16* __restrict__ outb,
                                                   int M, int N, int K) {
    __shared__ short As[128 * 64];
    __shared__ short Bs[128 * 64];
    const int tid = threadIdx.x;
    const int lane = tid & 63, wv = tid >> 6;       // 8 waves
    const int wm = wv >> 2, wn = wv & 3;            // 2 x 4
    const int m0 = blockIdx.x * 128, n0 = blockIdx.y * 128;
    const int lrow8 = lane >> 3;
    const int gchunk = ((lane & 7) ^ lrow8) * 8;
    const int lm = lane & 15, quad = lane >> 4;
    const int sw = lm & 7;
    int arow[2], apos[2], asrc[2];
    #pragma unroll
    for (int cc = 0; cc < 2; cc++) {
        int id = cc * 512 + tid;
        arow[cc] = id >> 3;
        apos[cc] = id & 7;
        asrc[cc] = (apos[cc] ^ (arow[cc] & 7)) * 8;
    }

    f32x4 acc[4][2];
    #pragma unroll
    for (int r = 0; r < 4; r++)
        #pragma unroll
        for (int c = 0; c < 2; c++) {
            f32x4 z = {0.f, 0.f, 0.f, 0.f};
            acc[r][c] = z;
        }

    s8v a0[2], a1[2];
    #pragma unroll
    for (int cc = 0; cc < 2; cc++) {
        a0[cc] = *(const s8v*)(p0 + (size_t)(m0 + arow[cc]) * K + asrc[cc]);
        a1[cc] = *(const s8v*)(p1 + (size_t)(m0 + arow[cc]) * K + asrc[cc]);
    }

    for (int k0 = 0; k0 < K; k0 += 64) {
        #pragma unroll
        for (int cc = 0; cc < 2; cc++) {
            s8v s;
            #pragma unroll
            for (int j = 0; j < 8; j++) s[j] = f2bs(s2f(a0[cc][j]) + s2f(a1[cc][j]));
            *(s8v*)&As[arow[cc] * 64 + apos[cc] * 8] = s;
        }
        #pragma unroll
        for (int cc = 0; cc < 2; cc++) {
            const int rb = wv * 16 + cc * 8;
            const bf16* gb = Bt + (size_t)(n0 + rb + lrow8) * K + k0 + gchunk;
            __builtin_amdgcn_global_load_lds(
                (const __attribute__((address_space(1))) void*)gb,
                (__attribute__((address_space(3))) void*)&Bs[rb * 64], 16, 0, 0);
        }
        __syncthreads();
        if (k0 + 64 < K) {
            #pragma unroll
            for (int cc = 0; cc < 2; cc++) {
                a0[cc] = *(const s8v*)(p0 + (size_t)(m0 + arow[cc]) * K + k0 + 64 +
                                       asrc[cc]);
                a1[cc] = *(const s8v*)(p1 + (size_t)(m0 + arow[cc]) * K + k0 + 64 +
                                       asrc[cc]);
            }
        }
        b8v af[4][2], bfr[2][2];
        #pragma unroll
        for (int r = 0; r < 4; r++)
            #pragma unroll
            for (int k = 0; k < 2; k++)
                af[r][k] = *(const b8v*)&As[(wm * 64 + r * 16 + lm) * 64 +
                                            (((k * 4 + quad) ^ sw) * 8)];
        #pragma unroll
        for (int c = 0; c < 2; c++)
            #pragma unroll
            for (int k = 0; k < 2; k++)
                bfr[c][k] = *(const b8v*)&Bs[(wn * 32 + c * 16 + lm) * 64 +
                                             (((k * 4 + quad) ^ sw) * 8)];
        #pragma unroll
        for (int r = 0; r < 4; r++)
            #pragma unroll
            for (int c = 0; c < 2; c++) {
                acc[r][c] = MFMA16(af[r][0], bfr[c][0], acc[r][c]);
                acc[r][c] = MFMA16(af[r][1], bfr[c][1], acc[r][c]);
            }
        __syncthreads();
    }

    #pragma unroll
    for (int r = 0; r < 4; r++) {
        const int mbase = m0 + wm * 64 + r * 16 + quad * 4;
        #pragma unroll
        for (int c = 0; c < 2; c++) {
            const int n = n0 + wn * 32 + c * 16 + lm;
            #pragma unroll
            for (int reg = 0; reg < 4; reg++) {
                const int m = mbase + reg;
                float v = acc[r][c][reg] + bias[n] + resf[(size_t)m * N + n];
                outb[(size_t)m * N + n] = f2b(v);
            }
        }
    }
}

// ---------------- Pass 1: Lr[s] = 1 / sum_{t>=s} exp(sc*q_t.k_s) ----------------
__global__ __launch_bounds__(512) void colsum_mfma(const bf16* __restrict__ qkv,
                                                   float* __restrict__ Lr) {
    __shared__ short Ks[64 * 72];
    __shared__ short Qs[2][64 * 72];
    __shared__ float red[4][64];
    const int tid = threadIdx.x, lane = tid & 63, wv = tid >> 6;
    const int wq = wv >> 1, wk = wv & 1;
    const int lm = lane & 15, quad = lane >> 4;
    const int bh = blockIdx.x, bb = bh >> 3, hh = bh & 7;
    const bf16* qbase = qkv + (size_t)bb * T_ * 1024 + hh * 64;
    const bf16* kbase = qbase + 512;
    const int r_ = tid >> 3, ch = tid & 7;
    for (int half = 0; half < 2; half++) {
        const int strip = half ? 31 - (int)blockIdx.y : (int)blockIdx.y;
        const int s0 = strip * 64;
        *(s8v*)&Ks[r_ * 72 + ch * 8] =
            *(const s8v*)(kbase + (size_t)(s0 + r_) * 1024 + ch * 8);
        s8v qr = *(const s8v*)(qbase + (size_t)(s0 + r_) * 1024 + ch * 8);
        b8v bk[2][2];
        float csum[2] = {};
        const int niter = 32 - strip;
        for (int it = 0; it < niter; it++) {
            const int buf = it & 1;
            *(s8v*)&Qs[buf][r_ * 72 + ch * 8] = qr;
            __syncthreads();
            if (it == 0) {
                #pragma unroll
                for (int c = 0; c < 2; c++)
                    #pragma unroll
                    for (int k = 0; k < 2; k++)
                        bk[c][k] = *(const b8v*)&Ks[(wk * 32 + c * 16 + lm) * 72 +
                                                    k * 32 + quad * 8];
            }
            if (it + 1 < niter) {
                const int t1 = s0 + (it + 1) * 64;
                qr = *(const s8v*)(qbase + (size_t)(t1 + r_) * 1024 + ch * 8);
            }
            const int t0 = s0 + it * 64;
            b8v aq[2];
            #pragma unroll
            for (int k = 0; k < 2; k++)
                aq[k] = *(const b8v*)&Qs[buf][(wq * 16 + lm) * 72 + k * 32 + quad * 8];
            if (it == 0) {  // diagonal: causal mask needed
                #pragma unroll
                for (int c = 0; c < 2; c++) {
                    f32x4 S = {0.f, 0.f, 0.f, 0.f};
                    S = MFMA16(aq[0], bk[c][0], S);
                    S = MFMA16(aq[1], bk[c][1], S);
                    const int s = s0 + wk * 32 + c * 16 + lm;
                    #pragma unroll
                    for (int reg = 0; reg < 4; reg++) {
                        int t = t0 + wq * 16 + quad * 4 + reg;
                        if (t >= s) csum[c] += EXP2F(S[reg] * SCALE2_);
                    }
                }
            } else {  // strictly below diagonal: no mask
                #pragma unroll
                for (int c = 0; c < 2; c++) {
                    f32x4 S = {0.f, 0.f, 0.f, 0.f};
                    S = MFMA16(aq[0], bk[c][0], S);
                    S = MFMA16(aq[1], bk[c][1], S);
                    csum[c] += EXP2F(S[0] * SCALE2_) + EXP2F(S[1] * SCALE2_) +
                               EXP2F(S[2] * SCALE2_) + EXP2F(S[3] * SCALE2_);
                }
            }
        }
        __syncthreads();
        #pragma unroll
        for (int c = 0; c < 2; c++) {
            float v = csum[c];
            v += __shfl_xor(v, 16);
            v += __shfl_xor(v, 32);
            if (lane < 16) red[wq][wk * 32 + c * 16 + lane] = v;
        }
        __syncthreads();
        if (tid < 64) {
            float s = red[0][tid] + red[1][tid] + red[2][tid] + red[3][tid];
            Lr[(size_t)bh * T_ + s0 + tid] = 1.0f / s;
        }
        __syncthreads();
    }
}

// ---------------- Pass 2: out_t = sum_{s<=t} exp(sc*q_t.k_s) * (v_s * Lr_s) ----------------
__global__ __launch_bounds__(512) void attnout_mfma(const bf16* __restrict__ qkv,
                                                    const bf16* __restrict__ vt,
                                                    const float* __restrict__ Lr,
                                                    bf16* __restrict__ pout0,
                                                    bf16* __restrict__ pout1) {
    __shared__ __align__(16) char arena[73728];
    short* const Qs = (short*)arena;                 // [128*72] 18432 B
    short* const Ps = (short*)(arena + 18432);       // [128*72] 18432 B
    short* const KV = (short*)(arena + 36864);       // Ks[2][64*72] Vt[2][64*72] 36864 B
    float* const Ored = (float*)(arena + 36864);     // [64*132] 33792 B (aliases KV)
    const int tid = threadIdx.x, lane = tid & 63, wv = tid >> 6;
    const int wm = wv >> 1, wn = wv & 1;
    const int lm = lane & 15, quad = lane >> 4;
    const int bh = blockIdx.x, bb = bh >> 3, hh = bh & 7;
    const int pairIdx = blockIdx.y >> 1, parity = blockIdx.y & 1;
    bf16* const outP = parity ? pout1 : pout0;
    const bf16* qbase = qkv + (size_t)bb * T_ * 1024 + hh * 64;
    const bf16* kbase = qbase + 512;
    const bf16* vtb = vt + ((size_t)bb * 512 + hh * 64) * T_;
    const float* Lrb = Lr + (size_t)bh * T_;
    const int r_ = tid >> 3, ch = tid & 7;
    for (int half = 0; half < 2; half++) {
        const int strip = half ? 15 - pairIdx : pairIdx;
        const int tb = strip * 128;
        #pragma unroll
        for (int cc = 0; cc < 2; cc++) {
            int idx = cc * 512 + tid, qr = idx >> 3, qc = idx & 7;
            *(s8v*)&Qs[qr * 72 + qc * 8] =
                *(const s8v*)(qbase + (size_t)(tb + qr) * 1024 + qc * 8);
        }
        int s0 = parity * 64;
        s8v kreg = *(const s8v*)(kbase + (size_t)(s0 + r_) * 1024 + ch * 8);
        s8v vreg = *(const s8v*)(vtb + (size_t)r_ * T_ + s0 + ch * 8);
        float4 lr0 = *(const float4*)(Lrb + s0 + ch * 8);
        float4 lr1 = *(const float4*)(Lrb + s0 + ch * 8 + 4);
        b8v bq[2][2];
        f32x4 o[2][4];
        #pragma unroll
        for (int r = 0; r < 2; r++)
            #pragma unroll
            for (int c = 0; c < 4; c++) {
                f32x4 z = {0.f, 0.f, 0.f, 0.f};
                o[r][c] = z;
            }
        const int niter = strip + 1;
        for (int it = 0; it < niter; it++) {
            s0 = (parity + 2 * it) * 64;
            const int buf = it & 1;
            short* const Ksb = KV + buf * (64 * 72);
            short* const Vsb = KV + 2 * (64 * 72) + buf * (64 * 72);
            uint4 vs;
            vs.x = pk2(s2f(vreg[0]) * lr0.x, s2f(vreg[1]) * lr0.y);
            vs.y = pk2(s2f(vreg[2]) * lr0.z, s2f(vreg[3]) * lr0.w);
            vs.z = pk2(s2f(vreg[4]) * lr1.x, s2f(vreg[5]) * lr1.y);
            vs.w = pk2(s2f(vreg[6]) * lr1.z, s2f(vreg[7]) * lr1.w);
            *(s8v*)&Ksb[r_ * 72 + ch * 8] = kreg;
            *(uint4*)&Vsb[r_ * 72 + ch * 8] = vs;
            __syncthreads();
            if (it == 0) {
                #pragma unroll
                for (int r = 0; r < 2; r++)
                    #pragma unroll
                    for (int k = 0; k < 2; k++)
                        bq[r][k] = *(const b8v*)&Qs[(wm * 32 + r * 16 + lm) * 72 +
                                                    k * 32 + quad * 8];
            }
            if (it + 1 < niter) {
                const int s1 = s0 + 128;
                kreg = *(const s8v*)(kbase + (size_t)(s1 + r_) * 1024 + ch * 8);
                vreg = *(const s8v*)(vtb + (size_t)r_ * T_ + s1 + ch * 8);
                lr0 = *(const float4*)(Lrb + s1 + ch * 8);
                lr1 = *(const float4*)(Lrb + s1 + ch * 8 + 4);
            }
            b8v ak[2][2];
            #pragma unroll
            for (int c = 0; c < 2; c++)
                #pragma unroll
                for (int k = 0; k < 2; k++)
                    ak[c][k] = *(const b8v*)&Ksb[(wn * 32 + c * 16 + lm) * 72 +
                                                 k * 32 + quad * 8];
            const bool masked = (it == niter - 1);
            #pragma unroll
            for (int r = 0; r < 2; r++) {
                const int t = tb + wm * 32 + r * 16 + lm;
                #pragma unroll
                for (int c = 0; c < 2; c++) {
                    f32x4 S = {0.f, 0.f, 0.f, 0.f};
                    S = MFMA16(ak[c][0], bq[r][0], S);
                    S = MFMA16(ak[c][1], bq[r][1], S);
                    float e[4];
                    #pragma unroll
                    for (int reg = 0; reg < 4; reg++)
                        e[reg] = EXP2F(S[reg] * SCALE2_);
                    if (masked) {
                        #pragma unroll
                        for (int reg = 0; reg < 4; reg++) {
                            int s = s0 + wn * 32 + c * 16 + quad * 4 + reg;
                            if (t < s) e[reg] = 0.f;
                        }
                    }
                    uint2 u;
                    u.x = pk2(e[0], e[1]);
                    u.y = pk2(e[2], e[3]);
                    *(uint2*)&Ps[(wm * 32 + r * 16 + lm) * 72 + wn * 32 + c * 16 +
                                 quad * 4] = u;
                }
            }
            #pragma unroll
            for (int r = 0; r < 2; r++) {
                b8v ap = *(const b8v*)&Ps[(wm * 32 + r * 16 + lm) * 72 + wn * 32 +
                                          quad * 8];
                #pragma unroll
                for (int c = 0; c < 4; c++) {
                    b8v bv = *(const b8v*)&Vsb[(c * 16 + lm) * 72 + wn * 32 + quad * 8];
                    o[r][c] = MFMA16(ap, bv, o[r][c]);
                }
            }
        }
        __syncthreads();
        if (wn == 1) {
            #pragma unroll
            for (int r = 0; r < 2; r++)
                #pragma unroll
                for (int c = 0; c < 4; c++)
                    *(f32x4*)&Ored[(c * 16 + lm) * 132 + wm * 32 + r * 16 + quad * 4] =
                        o[r][c];
        }
        __syncthreads();
        if (wn == 0) {
            #pragma unroll
            for (int r = 0; r < 2; r++)
                #pragma unroll
                for (int c = 0; c < 4; c++) {
                    f32x4 p = *(const f32x4*)&Ored[(c * 16 + lm) * 132 + wm * 32 +
                                                   r * 16 + quad * 4];
                    #pragma unroll
                    for (int reg = 0; reg < 4; reg++)
                        outP[(size_t)(bb * T_ + tb + wm * 32 + r * 16 + quad * 4 +
                                      reg) * C_ + hh * 64 + c * 16 + lm] =
                            f2b(o[r][c][reg] + p[reg]);
                }
        }
        __syncthreads();
    }
}

extern "C" void kernel_launch(void* const* d_in, const int* in_sizes, int n_in,
                              void* d_out, int out_size, void* d_ws, size_t ws_size,
                              hipStream_t stream) {
    const float* x   = (const float*)d_in[0];
    const float* Wq  = (const float*)d_in[1];
    const float* Wk  = (const float*)d_in[2];
    const float* Wv  = (const float*)d_in[3];
    const float* Wo  = (const float*)d_in[4];
    const float* bo  = (const float*)d_in[5];
    const float* W1  = (const float*)d_in[6];
    const float* b1  = (const float*)d_in[7];
    const float* W2  = (const float*)d_in[8];
    const float* b2  = (const float*)d_in[9];
    const float* g1  = (const float*)d_in[10];
    const float* be1 = (const float*)d_in[11];
    const float* g2  = (const float*)d_in[12];
    const float* be2 = (const float*)d_in[13];
    float* out = (float*)d_out;

    char* w = (char*)d_ws;
    auto alloc = [&](size_t bytes) -> void* {
        void* p = (void*)w;
        w += (bytes + 255) & ~(size_t)255;
        return p;
    };
    bf16* regionA = (bf16*)alloc((size_t)BT_ * 2048 * sizeof(bf16));  // 32MB
    bf16* qkvb = regionA;                                // [BT][1024] (q|k)
    bf16* hbuf = regionA + (size_t)BT_ * 1536;           // [BT][512] -> attn partial 0
    bf16* ff1  = regionA;                                // [BT][2048]
    bf16* x1     = (bf16*)alloc((size_t)BT_ * C_ * sizeof(bf16));
    bf16* h2     = (bf16*)alloc((size_t)BT_ * C_ * sizeof(bf16));    // attn p1 / W2 part0
    bf16* vt     = (bf16*)alloc((size_t)B_ * 512 * T_ * sizeof(bf16)); // W2 part1
    bf16* WqkvT  = (bf16*)alloc((size_t)1536 * C_ * sizeof(bf16));
    bf16* WoT    = (bf16*)alloc((size_t)C_ * C_ * sizeof(bf16));
    bf16* W1T    = (bf16*)alloc((size_t)C4_ * C_ * sizeof(bf16));
    bf16* W2T    = (bf16*)alloc((size_t)C_ * C4_ * sizeof(bf16));
    float* Lr    = (float*)alloc((size_t)B_ * H_ * T_ * sizeof(float));
    float2* st2  = (float2*)alloc((size_t)BT_ * sizeof(float2));     // LN2 stats
    bf16* g2b    = (bf16*)alloc(C_ * sizeof(bf16));
    bf16* be2b   = (bf16*)alloc(C_ * sizeof(bf16));
    bf16* partK  = h2;  // h2(8MB)+vt(8MB) contiguous = 16MB bf16 partials

    // 0+1. weight transposes + LN1 + g2/beta2 cvt in one launch
    prep_kernel<<<768 + BT_ + 1, 256, 0, stream>>>(Wq, Wk, Wv, Wo, W1, W2,
                                                   WqkvT, WoT, W1T, W2T,
                                                   x, g1, be1, hbuf, g2, be2,
                                                   g2b, be2b);
    // 2. QKV GEMM: [8192,1536,512]; q,k -> qkvb, v -> vt (transposed, coalesced)
    mfma_gemm<4><<<dim3(BT_ / 128, 1536 / 128), 256, 0, stream>>>(
        hbuf, WqkvT, nullptr, nullptr, qkvb, vt, BT_, 1536, C_);
    // 3. column-sum reciprocals (XCD-swizzled, 512 blocks)
    colsum_mfma<<<dim3(B_ * H_, 16), 512, 0, stream>>>(qkvb, Lr);
    // 4. attention output partials (XCD-swizzled, 512 blocks = 2/CU)
    attnout_mfma<<<dim3(B_ * H_, 16), 512, 0, stream>>>(qkvb, vt, Lr, hbuf, h2);
    // 5. x1 = x + (p0+p1) @ Wo + bo   (reduce_attn fused into A-staging)
    mfma_gemm2f<<<dim3(BT_ / 128, C_ / 128), 512, 0, stream>>>(
        hbuf, h2, WoT, bo, x, x1, BT_, C_, C_);
    // 6. LN2 stats only (normalization fused into W1's A-staging)
    ln_stats<<<BT_ / 4, 256, 0, stream>>>(x1, st2);
    // 7. ff1 = relu(LN(x1) @ W1 + b1)
    mfma_gemm_ln<<<dim3(BT_ / 128, C4_ / 128), 256, 0, stream>>>(
        x1, st2, g2b, be2b, W1T, b1, ff1, BT_, C4_, C_);
    // 8a. W2 split-K: partials (512 blocks -> 2/CU)
    mfma_gemm_sk<<<dim3(BT_ / 128, C_ / 128, 2), 256, 0, stream>>>(
        ff1, W2T, partK, BT_, C_, C4_, C4_ / 2);
    // 8b. out = p0 + p1 + b2 + x1
    reduce_w2<<<(BT_ * C_) / (256 * 8), 256, 0, stream>>>(partK, b2, x1, out);
}

// Round 15
// 248.805 us; speedup vs baseline: 1.0084x; 1.0084x over previous
//
#include <hip/hip_runtime.h>
#include <hip/hip_bf16.h>

// Block_4776003633552: transformer block, B=4 T=2048 C=512 H=8 D=64. fp32 I/O.
// Reference quirks: scale = C^-0.5; softmax over QUERY axis (axis=-2) =>
//   out_t = sum_{s<=t} exp(sc*q_t.k_s) * v_s / L_s,  L_s = sum_{t>=s} exp(sc*q_t.k_s).
// Round 15: fix r14's regression — mfma_gemm_ln now REGISTER-PREFETCHES the x1
// A-chunks one K-iter ahead (same pipeline shape as the proven mfma_gemm2f),
// removing ~700 cyc of exposed global-load latency per iteration. g2b/be2b
// loads stay at commit time (1KB each, L1-hot). Rest identical to r14.

typedef __hip_bfloat16 bf16;
typedef __bf16 b8v __attribute__((ext_vector_type(8)));   // MFMA A/B fragment (8 bf16)
typedef float  f32x4 __attribute__((ext_vector_type(4))); // MFMA C/D fragment
typedef short  s8v  __attribute__((ext_vector_type(8)));  // 16B bf16 copy chunk
typedef short  s4v  __attribute__((ext_vector_type(4)));  // 8B packed chunk

#define B_   4
#define T_   2048
#define C_   512
#define H_   8
#define D_   64
#define BT_  (B_ * T_)
#define C4_  (4 * C_)
#define EPS_ 1e-5f
#define SCALE2_ 0.06375872465908385f  // (1/sqrt(512)) * log2(e): exp(x*s)=2^(x*s*log2e)

#define MFMA16(a, b, c) __builtin_amdgcn_mfma_f32_16x16x32_bf16(a, b, c, 0, 0, 0)
#define EXP2F(x) __builtin_amdgcn_exp2f(x)

static __device__ __forceinline__ float b2f(bf16 x) { return __bfloat162float(x); }
static __device__ __forceinline__ bf16  f2b(float x) { return __float2bfloat16(x); }
static __device__ __forceinline__ short f2bs(float x) {
    bf16 h = f2b(x);
    return __builtin_bit_cast(short, h);
}
static __device__ __forceinline__ float s2f(short x) {
    return b2f(__builtin_bit_cast(bf16, x));
}
// packed 2xfp32 -> 2xbf16 (v_cvt_pk_bf16_f32); memcpy because __hip_bfloat162
// is not trivially copyable (bit_cast rejected).
static __device__ __forceinline__ unsigned int pk2(float a, float b) {
    float2 f;
    f.x = a;
    f.y = b;
    __hip_bfloat162 h = __float22bfloat162_rn(f);
    unsigned int u;
    __builtin_memcpy(&u, &h, 4);
    return u;
}

// ---------------- LayerNorm body (LN1, inside prep) ----------------
static __device__ __forceinline__ float ldv(const float* p) { return *p; }
static __device__ __forceinline__ float ldv(const bf16* p)  { return b2f(*p); }

template <typename TIN>
static __device__ __forceinline__ void ln_body(const TIN* __restrict__ xr,
                                               const float* __restrict__ g,
                                               const float* __restrict__ be,
                                               bf16* __restrict__ orow,
                                               float* ws, float* wsq) {
    const int tid = threadIdx.x;
    float v0 = ldv(xr + tid * 2);
    float v1 = ldv(xr + tid * 2 + 1);
    float s = v0 + v1;
    float sq = v0 * v0 + v1 * v1;
    #pragma unroll
    for (int o = 32; o > 0; o >>= 1) {
        s += __shfl_down(s, o);
        sq += __shfl_down(sq, o);
    }
    const int wid = tid >> 6, lane = tid & 63;
    if (lane == 0) { ws[wid] = s; wsq[wid] = sq; }
    __syncthreads();
    if (tid == 0) {
        float ts = 0.f, tq = 0.f;
        #pragma unroll
        for (int i = 0; i < 4; i++) { ts += ws[i]; tq += wsq[i]; }
        float mu = ts * (1.f / C_);
        float var = tq * (1.f / C_) - mu * mu;
        ws[4] = mu;
        wsq[4] = rsqrtf(var + EPS_);
    }
    __syncthreads();
    const float mu = ws[4], rstd = wsq[4];
    orow[tid * 2]     = f2b((v0 - mu) * rstd * g[tid * 2]     + be[tid * 2]);
    orow[tid * 2 + 1] = f2b((v1 - mu) * rstd * g[tid * 2 + 1] + be[tid * 2 + 1]);
}

// ---------------- ln_stats: per-row (mu, rstd) of x1; 4 rows/block ----------------
__global__ __launch_bounds__(256) void ln_stats(const bf16* __restrict__ x1,
                                                float2* __restrict__ stats) {
    const int tid = threadIdx.x, lane = tid & 63, wvi = tid >> 6;
    const int row = blockIdx.x * 4 + wvi;
    const bf16* xr = x1 + (size_t)row * C_;
    s8v v = *(const s8v*)(xr + lane * 8);
    float s = 0.f, sq = 0.f;
    #pragma unroll
    for (int j = 0; j < 8; j++) {
        float f = s2f(v[j]);
        s += f;
        sq += f * f;
    }
    #pragma unroll
    for (int o = 1; o < 64; o <<= 1) {
        s += __shfl_xor(s, o);
        sq += __shfl_xor(sq, o);
    }
    if (lane == 0) {
        float mu = s * (1.f / C_);
        float var = sq * (1.f / C_) - mu * mu;
        float2 st;
        st.x = mu;
        st.y = rsqrtf(var + EPS_);
        stats[row] = st;
    }
}

// ---------------- prep: weight transposes (768) + LN1 (8192) + g2/be2 cvt (1) ----------------
__global__ __launch_bounds__(256) void prep_kernel(const float* __restrict__ Wq,
                                                   const float* __restrict__ Wk,
                                                   const float* __restrict__ Wv,
                                                   const float* __restrict__ Wo,
                                                   const float* __restrict__ W1,
                                                   const float* __restrict__ W2,
                                                   bf16* __restrict__ WqkvT,
                                                   bf16* __restrict__ WoT,
                                                   bf16* __restrict__ W1T,
                                                   bf16* __restrict__ W2T,
                                                   const float* __restrict__ x,
                                                   const float* __restrict__ g1,
                                                   const float* __restrict__ be1,
                                                   bf16* __restrict__ hbuf,
                                                   const float* __restrict__ g2,
                                                   const float* __restrict__ be2,
                                                   bf16* __restrict__ g2b,
                                                   bf16* __restrict__ be2b) {
    __shared__ float Ts[64][65];
    __shared__ float ws[8], wsq[8];
    const int tid = threadIdx.x;
    const int id = blockIdx.x;
    if (id == 768 + BT_) {  // g2/beta2 -> bf16
        g2b[tid * 2] = f2b(g2[tid * 2]);
        g2b[tid * 2 + 1] = f2b(g2[tid * 2 + 1]);
        be2b[tid * 2] = f2b(be2[tid * 2]);
        be2b[tid * 2 + 1] = f2b(be2[tid * 2 + 1]);
        return;
    }
    if (id >= 768) {  // LN1
        const int row = id - 768;
        ln_body(x + (size_t)row * C_, g1, be1, hbuf + (size_t)row * C_, ws, wsq);
        return;
    }
    if (id < 192) {
        const int sub = id / 64, rem = id % 64;
        const int xx = rem & 7, hh = rem >> 3;
        const float* src = (sub == 0 ? Wq : sub == 1 ? Wk : Wv) + (size_t)hh * C_ * D_;
        bf16* dst = WqkvT + (size_t)sub * 512 * C_;
        const int c0 = xx * 64;
        #pragma unroll
        for (int p = 0; p < 16; p++) {
            int idx = p * 256 + tid, i = idx >> 6, j = idx & 63;
            Ts[i][j] = src[(size_t)(c0 + i) * D_ + j];
        }
        __syncthreads();
        #pragma unroll
        for (int p = 0; p < 16; p++) {
            int idx = p * 256 + tid, j = idx >> 6, i = idx & 63;
            dst[(size_t)(hh * 64 + j) * C_ + c0 + i] = f2b(Ts[i][j]);
        }
    } else {
        const float* src;
        bf16* dst;
        int r0, c0, R, Cc;
        if (id < 256) {
            int rem = id - 192;
            src = Wo; dst = WoT; R = 512; Cc = 512;
            r0 = (rem & 7) * 64; c0 = (rem >> 3) * 64;
        } else if (id < 512) {
            int rem = id - 256;
            src = W1; dst = W1T; R = 512; Cc = 2048;
            r0 = (rem & 7) * 64; c0 = (rem >> 3) * 64;
        } else {
            int rem = id - 512;
            src = W2; dst = W2T; R = 2048; Cc = 512;
            r0 = (rem & 31) * 64; c0 = (rem >> 5) * 64;
        }
        #pragma unroll
        for (int p = 0; p < 16; p++) {
            int idx = p * 256 + tid, i = idx >> 6, j = idx & 63;
            Ts[i][j] = src[(size_t)(r0 + i) * Cc + c0 + j];
        }
        __syncthreads();
        #pragma unroll
        for (int p = 0; p < 16; p++) {
            int idx = p * 256 + tid, j = idx >> 6, i = idx & 63;
            dst[(size_t)(c0 + j) * R + r0 + i] = f2b(Ts[i][j]);
        }
    }
}

// ---------------- MFMA GEMM (256 thr): C[M,N] = A[M,K] @ Bt[N,K]^T ----------------
// 128x128 tile, BK=64, XOR-swizzled LDS. 4 waves (2x2 of 64x64), 32 MFMA/iter.
// MODE 4: QKV split (q,k -> qkvb; v -> vt via LDS-transposed coalesced stores).
template <int MODE>
__global__ __launch_bounds__(256) void mfma_gemm(const bf16* __restrict__ A,
                                                 const bf16* __restrict__ Bt,
                                                 const float* __restrict__ bias,
                                                 bf16* __restrict__ outb,
                                                 bf16* __restrict__ qkvb,
                                                 bf16* __restrict__ vt,
                                                 int M, int N, int K) {
    constexpr int LBSZ = (MODE == 4) ? (128 * 136) : (2 * 128 * 64);
    __shared__ __align__(16) short LB[LBSZ];
    short* const As = LB;
    short* const Bs = LB + 128 * 64;
    const int tid = threadIdx.x;
    const int lane = tid & 63, wv = tid >> 6;
    const int wm = wv >> 1, wn = wv & 1;
    const int m0 = blockIdx.x * 128, n0 = blockIdx.y * 128;
    const int lrow8 = lane >> 3;              // row within 8-row band
    const int gchunk = ((lane & 7) ^ lrow8) * 8;  // swizzled global chunk (shorts)
    const int lm = lane & 15, quad = lane >> 4;
    const int sw = lm & 7;                    // read-side swizzle key

    f32x4 acc[4][4];
    #pragma unroll
    for (int r = 0; r < 4; r++)
        #pragma unroll
        for (int c = 0; c < 4; c++) {
            f32x4 z = {0.f, 0.f, 0.f, 0.f};
            acc[r][c] = z;
        }

    for (int k0 = 0; k0 < K; k0 += 64) {
        #pragma unroll
        for (int cc = 0; cc < 4; cc++) {
            const int rb = wv * 32 + cc * 8;  // wave-uniform base row
            const bf16* ga = A + (size_t)(m0 + rb + lrow8) * K + k0 + gchunk;
            __builtin_amdgcn_global_load_lds(
                (const __attribute__((address_space(1))) void*)ga,
                (__attribute__((address_space(3))) void*)&As[rb * 64], 16, 0, 0);
            const bf16* gb = Bt + (size_t)(n0 + rb + lrow8) * K + k0 + gchunk;
            __builtin_amdgcn_global_load_lds(
                (const __attribute__((address_space(1))) void*)gb,
                (__attribute__((address_space(3))) void*)&Bs[rb * 64], 16, 0, 0);
        }
        __syncthreads();
        b8v af[4][2], bfr[4][2];
        #pragma unroll
        for (int r = 0; r < 4; r++)
            #pragma unroll
            for (int k = 0; k < 2; k++)
                af[r][k] = *(const b8v*)&As[(wm * 64 + r * 16 + lm) * 64 +
                                            (((k * 4 + quad) ^ sw) * 8)];
        #pragma unroll
        for (int c = 0; c < 4; c++)
            #pragma unroll
            for (int k = 0; k < 2; k++)
                bfr[c][k] = *(const b8v*)&Bs[(wn * 64 + c * 16 + lm) * 64 +
                                             (((k * 4 + quad) ^ sw) * 8)];
        #pragma unroll
        for (int r = 0; r < 4; r++)
            #pragma unroll
            for (int c = 0; c < 4; c++) {
                acc[r][c] = MFMA16(af[r][0], bfr[c][0], acc[r][c]);
                acc[r][c] = MFMA16(af[r][1], bfr[c][1], acc[r][c]);
            }
        __syncthreads();
    }

    if (MODE == 4 && n0 >= 1024) {
        // V section: LDS-transpose (pitch 136) then coalesced 16B vt stores.
        short* const trans = LB;  // 128 x 136 (K-loop's final barrier guards reuse)
        #pragma unroll
        for (int r = 0; r < 4; r++) {
            const int ml = wm * 64 + r * 16 + quad * 4;
            #pragma unroll
            for (int c = 0; c < 4; c++) {
                const int nl = wn * 64 + c * 16 + lm;
                s4v p;
                #pragma unroll
                for (int reg = 0; reg < 4; reg++) p[reg] = f2bs(acc[r][c][reg]);
                *(s4v*)&trans[nl * 136 + ml] = p;
            }
        }
        __syncthreads();
        const int bb = m0 >> 11, t0loc = m0 & (T_ - 1);
        #pragma unroll
        for (int itb = 0; itb < 8; itb++) {
            int id = itb * 256 + tid;
            int nr = id >> 4, mc = id & 15;
            s8v v = *(const s8v*)&trans[nr * 136 + mc * 8];
            *(s8v*)&vt[((size_t)bb * 512 + (n0 - 1024) + nr) * T_ + t0loc + mc * 8] = v;
        }
        return;
    }

    #pragma unroll
    for (int r = 0; r < 4; r++) {
        const int mbase = m0 + wm * 64 + r * 16 + quad * 4;
        #pragma unroll
        for (int c = 0; c < 4; c++) {
            const int n = n0 + wn * 64 + c * 16 + lm;
            #pragma unroll
            for (int reg = 0; reg < 4; reg++) {
                const int m = mbase + reg;
                float v = acc[r][c][reg];
                if (MODE == 1) {
                    v += bias[n];
                    v = fmaxf(v, 0.f);
                    outb[(size_t)m * N + n] = f2b(v);
                } else {  // MODE 4 q/k section
                    qkvb[(size_t)m * 1024 + n] = f2b(v);
                }
            }
        }
    }
}

// ---------------- W1 GEMM with fused LN2: ff1 = relu(LN(x1) @ W1T^T + b1) ----------------
// A staged via VGPR with one-iter REGISTER PREFETCH (r14 post-mortem fix):
// x1 chunks for iter k+1 load right after the barrier, overlapping MFMA.
// g2b/be2b (1KB each, L1-hot) load at commit time. 256 thr, BK=64.
__global__ __launch_bounds__(256) void mfma_gemm_ln(const bf16* __restrict__ x1,
                                                    const float2* __restrict__ stats,
                                                    const bf16* __restrict__ g2b,
                                                    const bf16* __restrict__ be2b,
                                                    const bf16* __restrict__ Bt,
                                                    const float* __restrict__ bias,
                                                    bf16* __restrict__ outb,
                                                    int M, int N, int K) {
    __shared__ short As[128 * 64];
    __shared__ short Bs[128 * 64];
    const int tid = threadIdx.x;
    const int lane = tid & 63, wv = tid >> 6;
    const int wm = wv >> 1, wn = wv & 1;
    const int m0 = blockIdx.x * 128, n0 = blockIdx.y * 128;
    const int lrow8 = lane >> 3;
    const int gchunk = ((lane & 7) ^ lrow8) * 8;
    const int lm = lane & 15, quad = lane >> 4;
    const int sw = lm & 7;
    // A staging: 1024 chunks, 4 per thread; LDS pos p of row r holds chunk p^(r&7)
    int arow[4], apos[4], asrc[4];
    float2 st[4];
    #pragma unroll
    for (int cc = 0; cc < 4; cc++) {
        int id = cc * 256 + tid;
        arow[cc] = id >> 3;
        apos[cc] = id & 7;
        asrc[cc] = (apos[cc] ^ (arow[cc] & 7)) * 8;
        st[cc] = stats[m0 + arow[cc]];
    }

    f32x4 acc[4][4];
    #pragma unroll
    for (int r = 0; r < 4; r++)
        #pragma unroll
        for (int c = 0; c < 4; c++) {
            f32x4 z = {0.f, 0.f, 0.f, 0.f};
            acc[r][c] = z;
        }

    // preload iter-0 x1 chunks
    s8v xv[4];
    #pragma unroll
    for (int cc = 0; cc < 4; cc++)
        xv[cc] = *(const s8v*)(x1 + (size_t)(m0 + arow[cc]) * K + asrc[cc]);

    for (int k0 = 0; k0 < K; k0 += 64) {
        // normalize + commit A tile (xv prefetched; g/be L1-hot)
        #pragma unroll
        for (int cc = 0; cc < 4; cc++) {
            const int ch = k0 + asrc[cc];
            s8v gv = *(const s8v*)(g2b + ch);
            s8v bv = *(const s8v*)(be2b + ch);
            const float mu = st[cc].x, rstd = st[cc].y;
            s8v o;
            #pragma unroll
            for (int j = 0; j < 8; j++)
                o[j] = f2bs((s2f(xv[cc][j]) - mu) * rstd * s2f(gv[j]) + s2f(bv[j]));
            *(s8v*)&As[arow[cc] * 64 + apos[cc] * 8] = o;
        }
        // B via DMA
        #pragma unroll
        for (int cc = 0; cc < 4; cc++) {
            const int rb = wv * 32 + cc * 8;
            const bf16* gb = Bt + (size_t)(n0 + rb + lrow8) * K + k0 + gchunk;
            __builtin_amdgcn_global_load_lds(
                (const __attribute__((address_space(1))) void*)gb,
                (__attribute__((address_space(3))) void*)&Bs[rb * 64], 16, 0, 0);
        }
        __syncthreads();
        // prefetch next iter's x1 chunks (overlaps MFMA below)
        if (k0 + 64 < K) {
            #pragma unroll
            for (int cc = 0; cc < 4; cc++)
                xv[cc] = *(const s8v*)(x1 + (size_t)(m0 + arow[cc]) * K + k0 + 64 +
                                       asrc[cc]);
        }
        b8v af[4][2], bfr[4][2];
        #pragma unroll
        for (int r = 0; r < 4; r++)
            #pragma unroll
            for (int k = 0; k < 2; k++)
                af[r][k] = *(const b8v*)&As[(wm * 64 + r * 16 + lm) * 64 +
                                            (((k * 4 + quad) ^ sw) * 8)];
        #pragma unroll
        for (int c = 0; c < 4; c++)
            #pragma unroll
            for (int k = 0; k < 2; k++)
                bfr[c][k] = *(const b8v*)&Bs[(wn * 64 + c * 16 + lm) * 64 +
                                             (((k * 4 + quad) ^ sw) * 8)];
        #pragma unroll
        for (int r = 0; r < 4; r++)
            #pragma unroll
            for (int c = 0; c < 4; c++) {
                acc[r][c] = MFMA16(af[r][0], bfr[c][0], acc[r][c]);
                acc[r][c] = MFMA16(af[r][1], bfr[c][1], acc[r][c]);
            }
        __syncthreads();
    }

    #pragma unroll
    for (int r = 0; r < 4; r++) {
        const int mbase = m0 + wm * 64 + r * 16 + quad * 4;
        #pragma unroll
        for (int c = 0; c < 4; c++) {
            const int n = n0 + wn * 64 + c * 16 + lm;
            #pragma unroll
            for (int reg = 0; reg < 4; reg++) {
                const int m = mbase + reg;
                float v = acc[r][c][reg] + bias[n];
                v = fmaxf(v, 0.f);
                outb[(size_t)m * N + n] = f2b(v);
            }
        }
    }
}

// ---------------- Split-K MFMA GEMM: partial[z] = A[:, zKh:(z+1)Kh] @ Bt^T ----------------
__global__ __launch_bounds__(256) void mfma_gemm_sk(const bf16* __restrict__ A,
                                                    const bf16* __restrict__ Bt,
                                                    bf16* __restrict__ part,
                                                    int M, int N, int K, int Khalf) {
    __shared__ short As[128 * 64];
    __shared__ short Bs[128 * 64];
    const int tid = threadIdx.x;
    const int lane = tid & 63, wv = tid >> 6;
    const int wm = wv >> 1, wn = wv & 1;
    const int m0 = blockIdx.x * 128, n0 = blockIdx.y * 128;
    const int kbase = blockIdx.z * Khalf;
    const int lrow8 = lane >> 3;
    const int gchunk = ((lane & 7) ^ lrow8) * 8;
    const int lm = lane & 15, quad = lane >> 4;
    const int sw = lm & 7;

    f32x4 acc[4][4];
    #pragma unroll
    for (int r = 0; r < 4; r++)
        #pragma unroll
        for (int c = 0; c < 4; c++) {
            f32x4 z = {0.f, 0.f, 0.f, 0.f};
            acc[r][c] = z;
        }

    for (int kk = 0; kk < Khalf; kk += 64) {
        const int k0 = kbase + kk;
        #pragma unroll
        for (int cc = 0; cc < 4; cc++) {
            const int rb = wv * 32 + cc * 8;
            const bf16* ga = A + (size_t)(m0 + rb + lrow8) * K + k0 + gchunk;
            __builtin_amdgcn_global_load_lds(
                (const __attribute__((address_space(1))) void*)ga,
                (__attribute__((address_space(3))) void*)&As[rb * 64], 16, 0, 0);
            const bf16* gb = Bt + (size_t)(n0 + rb + lrow8) * K + k0 + gchunk;
            __builtin_amdgcn_global_load_lds(
                (const __attribute__((address_space(1))) void*)gb,
                (__attribute__((address_space(3))) void*)&Bs[rb * 64], 16, 0, 0);
        }
        __syncthreads();
        b8v af[4][2], bfr[4][2];
        #pragma unroll
        for (int r = 0; r < 4; r++)
            #pragma unroll
            for (int k = 0; k < 2; k++)
                af[r][k] = *(const b8v*)&As[(wm * 64 + r * 16 + lm) * 64 +
                                            (((k * 4 + quad) ^ sw) * 8)];
        #pragma unroll
        for (int c = 0; c < 4; c++)
            #pragma unroll
            for (int k = 0; k < 2; k++)
                bfr[c][k] = *(const b8v*)&Bs[(wn * 64 + c * 16 + lm) * 64 +
                                             (((k * 4 + quad) ^ sw) * 8)];
        #pragma unroll
        for (int r = 0; r < 4; r++)
            #pragma unroll
            for (int c = 0; c < 4; c++) {
                acc[r][c] = MFMA16(af[r][0], bfr[c][0], acc[r][c]);
                acc[r][c] = MFMA16(af[r][1], bfr[c][1], acc[r][c]);
            }
        __syncthreads();
    }

    bf16* pz = part + (size_t)blockIdx.z * M * N;
    #pragma unroll
    for (int r = 0; r < 4; r++) {
        const int mbase = m0 + wm * 64 + r * 16 + quad * 4;
        #pragma unroll
        for (int c = 0; c < 4; c++) {
            const int n = n0 + wn * 64 + c * 16 + lm;
            #pragma unroll
            for (int reg = 0; reg < 4; reg++)
                pz[(size_t)(mbase + reg) * N + n] = f2b(acc[r][c][reg]);
        }
    }
}

// ---------------- reduce: out = p0 + p1 + bias + res (fp32 out, 8-wide) ----------------
__global__ __launch_bounds__(256) void reduce_w2(const bf16* __restrict__ part,
                                                 const float* __restrict__ bias,
                                                 const bf16* __restrict__ res,
                                                 float* __restrict__ out) {
    const size_t i = ((size_t)blockIdx.x * 256 + threadIdx.x) * 8;
    const int n = (int)(i & (C_ - 1));
    s8v a = *(const s8v*)(part + i);
    s8v b = *(const s8v*)(part + (size_t)BT_ * C_ + i);
    s8v rv = *(const s8v*)(res + i);
    float4 bs0 = *(const float4*)(bias + n);
    float4 bs1 = *(const float4*)(bias + n + 4);
    float4 o0, o1;
    o0.x = s2f(a[0]) + s2f(b[0]) + bs0.x + s2f(rv[0]);
    o0.y = s2f(a[1]) + s2f(b[1]) + bs0.y + s2f(rv[1]);
    o0.z = s2f(a[2]) + s2f(b[2]) + bs0.z + s2f(rv[2]);
    o0.w = s2f(a[3]) + s2f(b[3]) + bs0.w + s2f(rv[3]);
    o1.x = s2f(a[4]) + s2f(b[4]) + bs1.x + s2f(rv[4]);
    o1.y = s2f(a[5]) + s2f(b[5]) + bs1.y + s2f(rv[5]);
    o1.z = s2f(a[6]) + s2f(b[6]) + bs1.z + s2f(rv[6]);
    o1.w = s2f(a[7]) + s2f(b[7]) + bs1.w + s2f(rv[7]);
    *(float4*)(out + i) = o0;
    *(float4*)(out + i + 4) = o1;
}

// ---------------- MFMA GEMM (512 thr) fused: x1 = (p0+p1)@WoT^T + bias + res ----------------
__global__ __launch_bounds__(512) void mfma_gemm2f(const bf16* __restrict__ p0,
                                                   const bf16* __restrict__ p1,
                                                   const bf16* __restrict__ Bt,
                                                   const float* __restrict__ bias,
                                                   const float* __restrict__ resf,
                                                   bf16* __restrict__ outb,
                                                   int M, int N, int K) {
    __shared__ short As[128 * 64];
    __shared__ short Bs[128 * 64];
    const int tid = threadIdx.x;
    const int lane = tid & 63, wv = tid >> 6;       // 8 waves
    const int wm = wv >> 2, wn = wv & 3;            // 2 x 4
    const int m0 = blockIdx.x * 128, n0 = blockIdx.y * 128;
    const int lrow8 = lane >> 3;
    const int gchunk = ((lane & 7) ^ lrow8) * 8;
    const int lm = lane & 15, quad = lane >> 4;
    const int sw = lm & 7;
    int arow[2], apos[2], asrc[2];
    #pragma unroll
    for (int cc = 0; cc < 2; cc++) {
        int id = cc * 512 + tid;
        arow[cc] = id >> 3;
        apos[cc] = id & 7;
        asrc[cc] = (apos[cc] ^ (arow[cc] & 7)) * 8;
    }

    f32x4 acc[4][2];
    #pragma unroll
    for (int r = 0; r < 4; r++)
        #pragma unroll
        for (int c = 0; c < 2; c++) {
            f32x4 z = {0.f, 0.f, 0.f, 0.f};
            acc[r][c] = z;
        }

    s8v a0[2], a1[2];
    #pragma unroll
    for (int cc = 0; cc < 2; cc++) {
        a0[cc] = *(const s8v*)(p0 + (size_t)(m0 + arow[cc]) * K + asrc[cc]);
        a1[cc] = *(const s8v*)(p1 + (size_t)(m0 + arow[cc]) * K + asrc[cc]);
    }

    for (int k0 = 0; k0 < K; k0 += 64) {
        #pragma unroll
        for (int cc = 0; cc < 2; cc++) {
            s8v s;
            #pragma unroll
            for (int j = 0; j < 8; j++) s[j] = f2bs(s2f(a0[cc][j]) + s2f(a1[cc][j]));
            *(s8v*)&As[arow[cc] * 64 + apos[cc] * 8] = s;
        }
        #pragma unroll
        for (int cc = 0; cc < 2; cc++) {
            const int rb = wv * 16 + cc * 8;
            const bf16* gb = Bt + (size_t)(n0 + rb + lrow8) * K + k0 + gchunk;
            __builtin_amdgcn_global_load_lds(
                (const __attribute__((address_space(1))) void*)gb,
                (__attribute__((address_space(3))) void*)&Bs[rb * 64], 16, 0, 0);
        }
        __syncthreads();
        if (k0 + 64 < K) {
            #pragma unroll
            for (int cc = 0; cc < 2; cc++) {
                a0[cc] = *(const s8v*)(p0 + (size_t)(m0 + arow[cc]) * K + k0 + 64 +
                                       asrc[cc]);
                a1[cc] = *(const s8v*)(p1 + (size_t)(m0 + arow[cc]) * K + k0 + 64 +
                                       asrc[cc]);
            }
        }
        b8v af[4][2], bfr[2][2];
        #pragma unroll
        for (int r = 0; r < 4; r++)
            #pragma unroll
            for (int k = 0; k < 2; k++)
                af[r][k] = *(const b8v*)&As[(wm * 64 + r * 16 + lm) * 64 +
                                            (((k * 4 + quad) ^ sw) * 8)];
        #pragma unroll
        for (int c = 0; c < 2; c++)
            #pragma unroll
            for (int k = 0; k < 2; k++)
                bfr[c][k] = *(const b8v*)&Bs[(wn * 32 + c * 16 + lm) * 64 +
                                             (((k * 4 + quad) ^ sw) * 8)];
        #pragma unroll
        for (int r = 0; r < 4; r++)
            #pragma unroll
            for (int c = 0; c < 2; c++) {
                acc[r][c] = MFMA16(af[r][0], bfr[c][0], acc[r][c]);
                acc[r][c] = MFMA16(af[r][1], bfr[c][1], acc[r][c]);
            }
        __syncthreads();
    }

    #pragma unroll
    for (int r = 0; r < 4; r++) {
        const int mbase = m0 + wm * 64 + r * 16 + quad * 4;
        #pragma unroll
        for (int c = 0; c < 2; c++) {
            const int n = n0 + wn * 32 + c * 16 + lm;
            #pragma unroll
            for (int reg = 0; reg < 4; reg++) {
                const int m = mbase + reg;
                float v = acc[r][c][reg] + bias[n] + resf[(size_t)m * N + n];
                outb[(size_t)m * N + n] = f2b(v);
            }
        }
    }
}

// ---------------- Pass 1: Lr[s] = 1 / sum_{t>=s} exp(sc*q_t.k_s) ----------------
__global__ __launch_bounds__(512) void colsum_mfma(const bf16* __restrict__ qkv,
                                                   float* __restrict__ Lr) {
    __shared__ short Ks[64 * 72];
    __shared__ short Qs[2][64 * 72];
    __shared__ float red[4][64];
    const int tid = threadIdx.x, lane = tid & 63, wv = tid >> 6;
    const int wq = wv >> 1, wk = wv & 1;
    const int lm = lane & 15, quad = lane >> 4;
    const int bh = blockIdx.x, bb = bh >> 3, hh = bh & 7;
    const bf16* qbase = qkv + (size_t)bb * T_ * 1024 + hh * 64;
    const bf16* kbase = qbase + 512;
    const int r_ = tid >> 3, ch = tid & 7;
    for (int half = 0; half < 2; half++) {
        const int strip = half ? 31 - (int)blockIdx.y : (int)blockIdx.y;
        const int s0 = strip * 64;
        *(s8v*)&Ks[r_ * 72 + ch * 8] =
            *(const s8v*)(kbase + (size_t)(s0 + r_) * 1024 + ch * 8);
        s8v qr = *(const s8v*)(qbase + (size_t)(s0 + r_) * 1024 + ch * 8);
        b8v bk[2][2];
        float csum[2] = {};
        const int niter = 32 - strip;
        for (int it = 0; it < niter; it++) {
            const int buf = it & 1;
            *(s8v*)&Qs[buf][r_ * 72 + ch * 8] = qr;
            __syncthreads();
            if (it == 0) {
                #pragma unroll
                for (int c = 0; c < 2; c++)
                    #pragma unroll
                    for (int k = 0; k < 2; k++)
                        bk[c][k] = *(const b8v*)&Ks[(wk * 32 + c * 16 + lm) * 72 +
                                                    k * 32 + quad * 8];
            }
            if (it + 1 < niter) {
                const int t1 = s0 + (it + 1) * 64;
                qr = *(const s8v*)(qbase + (size_t)(t1 + r_) * 1024 + ch * 8);
            }
            const int t0 = s0 + it * 64;
            b8v aq[2];
            #pragma unroll
            for (int k = 0; k < 2; k++)
                aq[k] = *(const b8v*)&Qs[buf][(wq * 16 + lm) * 72 + k * 32 + quad * 8];
            if (it == 0) {  // diagonal: causal mask needed
                #pragma unroll
                for (int c = 0; c < 2; c++) {
                    f32x4 S = {0.f, 0.f, 0.f, 0.f};
                    S = MFMA16(aq[0], bk[c][0], S);
                    S = MFMA16(aq[1], bk[c][1], S);
                    const int s = s0 + wk * 32 + c * 16 + lm;
                    #pragma unroll
                    for (int reg = 0; reg < 4; reg++) {
                        int t = t0 + wq * 16 + quad * 4 + reg;
                        if (t >= s) csum[c] += EXP2F(S[reg] * SCALE2_);
                    }
                }
            } else {  // strictly below diagonal: no mask
                #pragma unroll
                for (int c = 0; c < 2; c++) {
                    f32x4 S = {0.f, 0.f, 0.f, 0.f};
                    S = MFMA16(aq[0], bk[c][0], S);
                    S = MFMA16(aq[1], bk[c][1], S);
                    csum[c] += EXP2F(S[0] * SCALE2_) + EXP2F(S[1] * SCALE2_) +
                               EXP2F(S[2] * SCALE2_) + EXP2F(S[3] * SCALE2_);
                }
            }
        }
        __syncthreads();
        #pragma unroll
        for (int c = 0; c < 2; c++) {
            float v = csum[c];
            v += __shfl_xor(v, 16);
            v += __shfl_xor(v, 32);
            if (lane < 16) red[wq][wk * 32 + c * 16 + lane] = v;
        }
        __syncthreads();
        if (tid < 64) {
            float s = red[0][tid] + red[1][tid] + red[2][tid] + red[3][tid];
            Lr[(size_t)bh * T_ + s0 + tid] = 1.0f / s;
        }
        __syncthreads();
    }
}

// ---------------- Pass 2: out_t = sum_{s<=t} exp(sc*q_t.k_s) * (v_s * Lr_s) ----------------
__global__ __launch_bounds__(512) void attnout_mfma(const bf16* __restrict__ qkv,
                                                    const bf16* __restrict__ vt,
                                                    const float* __restrict__ Lr,
                                                    bf16* __restrict__ pout0,
                                                    bf16* __restrict__ pout1) {
    __shared__ __align__(16) char arena[73728];
    short* const Qs = (short*)arena;                 // [128*72] 18432 B
    short* const Ps = (short*)(arena + 18432);       // [128*72] 18432 B
    short* const KV = (short*)(arena + 36864);       // Ks[2][64*72] Vt[2][64*72] 36864 B
    float* const Ored = (float*)(arena + 36864);     // [64*132] 33792 B (aliases KV)
    const int tid = threadIdx.x, lane = tid & 63, wv = tid >> 6;
    const int wm = wv >> 1, wn = wv & 1;
    const int lm = lane & 15, quad = lane >> 4;
    const int bh = blockIdx.x, bb = bh >> 3, hh = bh & 7;
    const int pairIdx = blockIdx.y >> 1, parity = blockIdx.y & 1;
    bf16* const outP = parity ? pout1 : pout0;
    const bf16* qbase = qkv + (size_t)bb * T_ * 1024 + hh * 64;
    const bf16* kbase = qbase + 512;
    const bf16* vtb = vt + ((size_t)bb * 512 + hh * 64) * T_;
    const float* Lrb = Lr + (size_t)bh * T_;
    const int r_ = tid >> 3, ch = tid & 7;
    for (int half = 0; half < 2; half++) {
        const int strip = half ? 15 - pairIdx : pairIdx;
        const int tb = strip * 128;
        #pragma unroll
        for (int cc = 0; cc < 2; cc++) {
            int idx = cc * 512 + tid, qr = idx >> 3, qc = idx & 7;
            *(s8v*)&Qs[qr * 72 + qc * 8] =
                *(const s8v*)(qbase + (size_t)(tb + qr) * 1024 + qc * 8);
        }
        int s0 = parity * 64;
        s8v kreg = *(const s8v*)(kbase + (size_t)(s0 + r_) * 1024 + ch * 8);
        s8v vreg = *(const s8v*)(vtb + (size_t)r_ * T_ + s0 + ch * 8);
        float4 lr0 = *(const float4*)(Lrb + s0 + ch * 8);
        float4 lr1 = *(const float4*)(Lrb + s0 + ch * 8 + 4);
        b8v bq[2][2];
        f32x4 o[2][4];
        #pragma unroll
        for (int r = 0; r < 2; r++)
            #pragma unroll
            for (int c = 0; c < 4; c++) {
                f32x4 z = {0.f, 0.f, 0.f, 0.f};
                o[r][c] = z;
            }
        const int niter = strip + 1;
        for (int it = 0; it < niter; it++) {
            s0 = (parity + 2 * it) * 64;
            const int buf = it & 1;
            short* const Ksb = KV + buf * (64 * 72);
            short* const Vsb = KV + 2 * (64 * 72) + buf * (64 * 72);
            uint4 vs;
            vs.x = pk2(s2f(vreg[0]) * lr0.x, s2f(vreg[1]) * lr0.y);
            vs.y = pk2(s2f(vreg[2]) * lr0.z, s2f(vreg[3]) * lr0.w);
            vs.z = pk2(s2f(vreg[4]) * lr1.x, s2f(vreg[5]) * lr1.y);
            vs.w = pk2(s2f(vreg[6]) * lr1.z, s2f(vreg[7]) * lr1.w);
            *(s8v*)&Ksb[r_ * 72 + ch * 8] = kreg;
            *(uint4*)&Vsb[r_ * 72 + ch * 8] = vs;
            __syncthreads();
            if (it == 0) {
                #pragma unroll
                for (int r = 0; r < 2; r++)
                    #pragma unroll
                    for (int k = 0; k < 2; k++)
                        bq[r][k] = *(const b8v*)&Qs[(wm * 32 + r * 16 + lm) * 72 +
                                                    k * 32 + quad * 8];
            }
            if (it + 1 < niter) {
                const int s1 = s0 + 128;
                kreg = *(const s8v*)(kbase + (size_t)(s1 + r_) * 1024 + ch * 8);
                vreg = *(const s8v*)(vtb + (size_t)r_ * T_ + s1 + ch * 8);
                lr0 = *(const float4*)(Lrb + s1 + ch * 8);
                lr1 = *(const float4*)(Lrb + s1 + ch * 8 + 4);
            }
            b8v ak[2][2];
            #pragma unroll
            for (int c = 0; c < 2; c++)
                #pragma unroll
                for (int k = 0; k < 2; k++)
                    ak[c][k] = *(const b8v*)&Ksb[(wn * 32 + c * 16 + lm) * 72 +
                                                 k * 32 + quad * 8];
            const bool masked = (it == niter - 1);
            #pragma unroll
            for (int r = 0; r < 2; r++) {
                const int t = tb + wm * 32 + r * 16 + lm;
                #pragma unroll
                for (int c = 0; c < 2; c++) {
                    f32x4 S = {0.f, 0.f, 0.f, 0.f};
                    S = MFMA16(ak[c][0], bq[r][0], S);
                    S = MFMA16(ak[c][1], bq[r][1], S);
                    float e[4];
                    #pragma unroll
                    for (int reg = 0; reg < 4; reg++)
                        e[reg] = EXP2F(S[reg] * SCALE2_);
                    if (masked) {
                        #pragma unroll
                        for (int reg = 0; reg < 4; reg++) {
                            int s = s0 + wn * 32 + c * 16 + quad * 4 + reg;
                            if (t < s) e[reg] = 0.f;
                        }
                    }
                    uint2 u;
                    u.x = pk2(e[0], e[1]);
                    u.y = pk2(e[2], e[3]);
                    *(uint2*)&Ps[(wm * 32 + r * 16 + lm) * 72 + wn * 32 + c * 16 +
                                 quad * 4] = u;
                }
            }
            #pragma unroll
            for (int r = 0; r < 2; r++) {
                b8v ap = *(const b8v*)&Ps[(wm * 32 + r * 16 + lm) * 72 + wn * 32 +
                                          quad * 8];
                #pragma unroll
                for (int c = 0; c < 4; c++) {
                    b8v bv = *(const b8v*)&Vsb[(c * 16 + lm) * 72 + wn * 32 + quad * 8];
                    o[r][c] = MFMA16(ap, bv, o[r][c]);
                }
            }
        }
        __syncthreads();
        if (wn == 1) {
            #pragma unroll
            for (int r = 0; r < 2; r++)
                #pragma unroll
                for (int c = 0; c < 4; c++)
                    *(f32x4*)&Ored[(c * 16 + lm) * 132 + wm * 32 + r * 16 + quad * 4] =
                        o[r][c];
        }
        __syncthreads();
        if (wn == 0) {
            #pragma unroll
            for (int r = 0; r < 2; r++)
                #pragma unroll
                for (int c = 0; c < 4; c++) {
                    f32x4 p = *(const f32x4*)&Ored[(c * 16 + lm) * 132 + wm * 32 +
                                                   r * 16 + quad * 4];
                    #pragma unroll
                    for (int reg = 0; reg < 4; reg++)
                        outP[(size_t)(bb * T_ + tb + wm * 32 + r * 16 + quad * 4 +
                                      reg) * C_ + hh * 64 + c * 16 + lm] =
                            f2b(o[r][c][reg] + p[reg]);
                }
        }
        __syncthreads();
    }
}

extern "C" void kernel_launch(void* const* d_in, const int* in_sizes, int n_in,
                              void* d_out, int out_size, void* d_ws, size_t ws_size,
                              hipStream_t stream) {
    const float* x   = (const float*)d_in[0];
    const float* Wq  = (const float*)d_in[1];
    const float* Wk  = (const float*)d_in[2];
    const float* Wv  = (const float*)d_in[3];
    const float* Wo  = (const float*)d_in[4];
    const float* bo  = (const float*)d_in[5];
    const float* W1  = (const float*)d_in[6];
    const float* b1  = (const float*)d_in[7];
    const float* W2  = (const float*)d_in[8];
    const float* b2  = (const float*)d_in[9];
    const float* g1  = (const float*)d_in[10];
    const float* be1 = (const float*)d_in[11];
    const float* g2  = (const float*)d_in[12];
    const float* be2 = (const float*)d_in[13];
    float* out = (float*)d_out;

    char* w = (char*)d_ws;
    auto alloc = [&](size_t bytes) -> void* {
        void* p = (void*)w;
        w += (bytes + 255) & ~(size_t)255;
        return p;
    };
    bf16* regionA = (bf16*)alloc((size_t)BT_ * 2048 * sizeof(bf16));  // 32MB
    bf16* qkvb = regionA;                                // [BT][1024] (q|k)
    bf16* hbuf = regionA + (size_t)BT_ * 1536;           // [BT][512] -> attn partial 0
    bf16* ff1  = regionA;                                // [BT][2048]
    bf16* x1     = (bf16*)alloc((size_t)BT_ * C_ * sizeof(bf16));
    bf16* h2     = (bf16*)alloc((size_t)BT_ * C_ * sizeof(bf16));    // attn p1 / W2 part0
    bf16* vt     = (bf16*)alloc((size_t)B_ * 512 * T_ * sizeof(bf16)); // W2 part1
    bf16* WqkvT  = (bf16*)alloc((size_t)1536 * C_ * sizeof(bf16));
    bf16* WoT    = (bf16*)alloc((size_t)C_ * C_ * sizeof(bf16));
    bf16* W1T    = (bf16*)alloc((size_t)C4_ * C_ * sizeof(bf16));
    bf16* W2T    = (bf16*)alloc((size_t)C_ * C4_ * sizeof(bf16));
    float* Lr    = (float*)alloc((size_t)B_ * H_ * T_ * sizeof(float));
    float2* st2  = (float2*)alloc((size_t)BT_ * sizeof(float2));     // LN2 stats
    bf16* g2b    = (bf16*)alloc(C_ * sizeof(bf16));
    bf16* be2b   = (bf16*)alloc(C_ * sizeof(bf16));
    bf16* partK  = h2;  // h2(8MB)+vt(8MB) contiguous = 16MB bf16 partials

    // 0+1. weight transposes + LN1 + g2/beta2 cvt in one launch
    prep_kernel<<<768 + BT_ + 1, 256, 0, stream>>>(Wq, Wk, Wv, Wo, W1, W2,
                                                   WqkvT, WoT, W1T, W2T,
                                                   x, g1, be1, hbuf, g2, be2,
                                                   g2b, be2b);
    // 2. QKV GEMM: [8192,1536,512]; q,k -> qkvb, v -> vt (transposed, coalesced)
    mfma_gemm<4><<<dim3(BT_ / 128, 1536 / 128), 256, 0, stream>>>(
        hbuf, WqkvT, nullptr, nullptr, qkvb, vt, BT_, 1536, C_);
    // 3. column-sum reciprocals (XCD-swizzled, 512 blocks)
    colsum_mfma<<<dim3(B_ * H_, 16), 512, 0, stream>>>(qkvb, Lr);
    // 4. attention output partials (XCD-swizzled, 512 blocks = 2/CU)
    attnout_mfma<<<dim3(B_ * H_, 16), 512, 0, stream>>>(qkvb, vt, Lr, hbuf, h2);
    // 5. x1 = x + (p0+p1) @ Wo + bo   (reduce_attn fused into A-staging)
    mfma_gemm2f<<<dim3(BT_ / 128, C_ / 128), 512, 0, stream>>>(
        hbuf, h2, WoT, bo, x, x1, BT_, C_, C_);
    // 6. LN2 stats only (normalization fused into W1's A-staging)
    ln_stats<<<BT_ / 4, 256, 0, stream>>>(x1, st2);
    // 7. ff1 = relu(LN(x1) @ W1 + b1)
    mfma_gemm_ln<<<dim3(BT_ / 128, C4_ / 128), 256, 0, stream>>>(
        x1, st2, g2b, be2b, W1T, b1, ff1, BT_, C4_, C_);
    // 8a. W2 split-K: partials (512 blocks -> 2/CU)
    mfma_gemm_sk<<<dim3(BT_ / 128, C_ / 128, 2), 256, 0, stream>>>(
        ff1, W2T, partK, BT_, C_, C4_, C4_ / 2);
    // 8b. out = p0 + p1 + b2 + x1
    reduce_w2<<<(BT_ * C_) / (256 * 8), 256, 0, stream>>>(partK, b2, x1, out);
}